// Round 1
// baseline (655.906 us; speedup 1.0000x reference)
//
#include <hip/hip_runtime.h>
#include <hip/hip_bf16.h>

// Problem constants
#define DIMC   1024
#define HEADS  16
#define HDIM   64
#define NTOK   64
#define BTOT   512
#define TABL   15

typedef __attribute__((ext_vector_type(8))) short short8;
typedef __attribute__((ext_vector_type(4))) float f32x4;
typedef __attribute__((ext_vector_type(8))) unsigned short u16x8;

static __device__ __forceinline__ void gload_lds16(const void* g, void* l) {
    __builtin_amdgcn_global_load_lds((const __attribute__((address_space(1))) void*)g,
                                     (__attribute__((address_space(3))) void*)l, 16, 0, 0);
}

static __device__ __forceinline__ unsigned short f2bf(float f) {
    __hip_bfloat16 h = __float2bfloat16(f);
    return *(unsigned short*)&h;
}

// ---------------- fp32 -> bf16 convert ----------------
__global__ void cvt_kernel(const float* __restrict__ in, unsigned short* __restrict__ out, int n4) {
    int stride = gridDim.x * blockDim.x;
    for (int i = blockIdx.x * blockDim.x + threadIdx.x; i < n4; i += stride) {
        float4 v = ((const float4*)in)[i];
        ushort4 o;
        o.x = f2bf(v.x); o.y = f2bf(v.y); o.z = f2bf(v.z); o.w = f2bf(v.w);
        ((ushort4*)out)[i] = o;
    }
}

// ---------------- GEMM: C[m][f] = sum_k A[m][k]*B[f][k] + bias[f] ----------------
// A: [M][1024] bf16, B: [NMAT][1024] bf16 (row-major, K contiguous)
// MODE 0: bf16 out, scale cols f<1024 by 0.125 (q)    MODE 1: fp32 out
template<int NMAT, int MODE>
__global__ __launch_bounds__(256, 2)
void gemm_bt(const unsigned short* __restrict__ A,
             const unsigned short* __restrict__ B,
             const float* __restrict__ bias,
             float* __restrict__ Cf, unsigned short* __restrict__ Cb)
{
    constexpr int K  = 1024;
    constexpr int BK = 32;
    __shared__ unsigned short Al[128 * BK];
    __shared__ unsigned short Bl[128 * BK];

    const int nbn  = NMAT / 128;
    const int bm   = blockIdx.x / nbn;
    const int bn   = blockIdx.x % nbn;
    const int tid  = threadIdx.x;
    const int lane = tid & 63;
    const int w    = tid >> 6;
    const int wm   = w >> 1, wn = w & 1;
    const int l15  = lane & 15, lg = lane >> 4;

    f32x4 acc[4][4] = {};

    const int rsub = lane >> 2;          // row within 16-row segment
    const int kcol = (lane & 3) * 8;     // bf16 elems within 32-col row
    const unsigned short* gA = A + (size_t)(bm * 128) * K;
    const unsigned short* gB = B + (size_t)(bn * 128) * K;

    for (int kt = 0; kt < K / BK; ++kt) {
        const int k0 = kt * BK;
        #pragma unroll
        for (int s = 0; s < 2; ++s) {
            int seg = w * 2 + s;
            int row = seg * 16 + rsub;
            gload_lds16(gA + (size_t)row * K + k0 + kcol, (char*)Al + seg * 1024);
            gload_lds16(gB + (size_t)row * K + k0 + kcol, (char*)Bl + seg * 1024);
        }
        __syncthreads();
        short8 af[4], bfr[4];
        #pragma unroll
        for (int mt = 0; mt < 4; ++mt)
            af[mt] = *(const short8*)&Al[(wm * 64 + mt * 16 + l15) * BK + lg * 8];
        #pragma unroll
        for (int nt = 0; nt < 4; ++nt)
            bfr[nt] = *(const short8*)&Bl[(wn * 64 + nt * 16 + l15) * BK + lg * 8];
        #pragma unroll
        for (int mt = 0; mt < 4; ++mt)
            #pragma unroll
            for (int nt = 0; nt < 4; ++nt)
                acc[mt][nt] = __builtin_amdgcn_mfma_f32_16x16x32_bf16(af[mt], bfr[nt], acc[mt][nt], 0, 0, 0);
        __syncthreads();
    }

    #pragma unroll
    for (int mt = 0; mt < 4; ++mt) {
        #pragma unroll
        for (int nt = 0; nt < 4; ++nt) {
            const int f = bn * 128 + wn * 64 + nt * 16 + l15;
            const float bv = bias[f];
            #pragma unroll
            for (int r = 0; r < 4; ++r) {
                const int m = bm * 128 + wm * 64 + mt * 16 + lg * 4 + r;
                float val = acc[mt][nt][r] + bv;
                if (MODE == 0) {
                    if (f < 1024) val *= 0.125f;   // q scale = HD^-0.5
                    Cb[(size_t)m * NMAT + f] = f2bf(val);
                } else {
                    Cf[(size_t)m * NMAT + f] = val;
                }
            }
        }
    }
}

// ---------------- attention: one block per (window, head) ----------------
// qkv: [32768][3072] bf16 (f = t*1024 + h*64 + d).  o: [32768][1024] bf16 (col h*64+d)
__global__ __launch_bounds__(256, 2)
void attn_kernel(const unsigned short* __restrict__ qkv,
                 const float* __restrict__ theta_max,
                 const float* __restrict__ a_p, const float* __restrict__ b_p,
                 const float* __restrict__ a_r, const float* __restrict__ b_r,
                 unsigned short* __restrict__ o_ws)
{
    const int bh = blockIdx.x;
    const int b  = bh >> 4;
    const int h  = bh & 15;
    const int tid = threadIdx.x, lane = tid & 63, w = tid >> 6;
    const int l15 = lane & 15, lg = lane >> 4;

    __shared__ unsigned short ql[64 * 64];
    __shared__ unsigned short kl[64 * 64];
    __shared__ unsigned short vtl[64 * 64];   // transposed: vtl[d][j]
    __shared__ float S[64 * 64];
    __shared__ unsigned short P[64 * 64];
    __shared__ float phiTab[15], thetaTab[15];

    // bias tables: 15 azimuth values, 15 radius values
    if (tid < 15) {
        int az = tid - 7;
        int azm = az < 0 ? az + 15 : az;
        float ang = (float)az * 0.09817477042468103f;   // 2*pi/64
        phiTab[tid] = a_p[azm * 16 + h] * cosf(ang) + b_p[azm * 16 + h] * sinf(ang);
    } else if (tid >= 32 && tid < 47) {
        int rr = tid - 39;                               // [-7,7]
        int rm = rr < 0 ? rr + 15 : rr;
        float rn = (float)rr * theta_max[b >> 6] * 0.015625f;   // /64
        thetaTab[tid - 32] = a_r[rm * 16 + h] * cosf(rn) + b_r[rm * 16 + h] * sinf(rn);
    }

    // stage q, k (linear), v (transposed)
    const unsigned short* qg = qkv + (size_t)b * 64 * 3072 + h * 64;
    const unsigned short* kg = qg + 1024;
    const unsigned short* vg = qg + 2048;
    #pragma unroll
    for (int rep = 0; rep < 2; ++rep) {
        int idx = tid + rep * 256;       // 0..511
        int row = idx >> 3, seg = idx & 7;
        *(float4*)&ql[row * 64 + seg * 8] = *(const float4*)&qg[(size_t)row * 3072 + seg * 8];
        *(float4*)&kl[row * 64 + seg * 8] = *(const float4*)&kg[(size_t)row * 3072 + seg * 8];
        u16x8 vv = *(const u16x8*)&vg[(size_t)row * 3072 + seg * 8];
        #pragma unroll
        for (int e = 0; e < 8; ++e)
            vtl[(seg * 8 + e) * 64 + row] = vv[e];
    }
    __syncthreads();

    // S = q @ k^T  (64x64, K=64) ; wave w owns rows w*16..w*16+15
    short8 aq[2];
    #pragma unroll
    for (int kc = 0; kc < 2; ++kc)
        aq[kc] = *(const short8*)&ql[(w * 16 + l15) * 64 + kc * 32 + lg * 8];
    f32x4 sacc[4] = {};
    #pragma unroll
    for (int nt = 0; nt < 4; ++nt)
        #pragma unroll
        for (int kc = 0; kc < 2; ++kc) {
            short8 bk = *(const short8*)&kl[(nt * 16 + l15) * 64 + kc * 32 + lg * 8];
            sacc[nt] = __builtin_amdgcn_mfma_f32_16x16x32_bf16(aq[kc], bk, sacc[nt], 0, 0, 0);
        }

    // add bias, write S
    #pragma unroll
    for (int nt = 0; nt < 4; ++nt)
        #pragma unroll
        for (int r = 0; r < 4; ++r) {
            int i = w * 16 + lg * 4 + r;
            int j = nt * 16 + l15;
            int az = (i & 7) - (j & 7);
            int rr = (i >> 3) - (j >> 3);
            S[i * 64 + j] = sacc[nt][r] + phiTab[az + 7] + thetaTab[rr + 7];
        }
    __syncthreads();

    // softmax: 4 lanes per row, 16 elems each
    {
        int row = tid >> 2, q4 = tid & 3;
        float x[16];
        #pragma unroll
        for (int t = 0; t < 4; ++t) {
            float4 v = *(const float4*)&S[row * 64 + q4 * 16 + t * 4];
            x[t * 4 + 0] = v.x; x[t * 4 + 1] = v.y; x[t * 4 + 2] = v.z; x[t * 4 + 3] = v.w;
        }
        float mx = x[0];
        #pragma unroll
        for (int t = 1; t < 16; ++t) mx = fmaxf(mx, x[t]);
        mx = fmaxf(mx, __shfl_xor(mx, 1));
        mx = fmaxf(mx, __shfl_xor(mx, 2));
        float sum = 0.f;
        #pragma unroll
        for (int t = 0; t < 16; ++t) { x[t] = expf(x[t] - mx); sum += x[t]; }
        sum += __shfl_xor(sum, 1);
        sum += __shfl_xor(sum, 2);
        float inv = 1.0f / sum;
        #pragma unroll
        for (int t = 0; t < 16; ++t)
            P[row * 64 + q4 * 16 + t] = f2bf(x[t] * inv);
    }
    __syncthreads();

    // O = P @ V   (A = P rows i, B[k=j][n=d] = vtl[d][j])
    short8 ap[2];
    #pragma unroll
    for (int kc = 0; kc < 2; ++kc)
        ap[kc] = *(const short8*)&P[(w * 16 + l15) * 64 + kc * 32 + lg * 8];
    f32x4 oacc[4] = {};
    #pragma unroll
    for (int dt = 0; dt < 4; ++dt)
        #pragma unroll
        for (int kc = 0; kc < 2; ++kc) {
            short8 bv = *(const short8*)&vtl[(dt * 16 + l15) * 64 + kc * 32 + lg * 8];
            oacc[dt] = __builtin_amdgcn_mfma_f32_16x16x32_bf16(ap[kc], bv, oacc[dt], 0, 0, 0);
        }
    #pragma unroll
    for (int dt = 0; dt < 4; ++dt)
        #pragma unroll
        for (int r = 0; r < 4; ++r) {
            int i = w * 16 + lg * 4 + r;
            int d = dt * 16 + l15;
            o_ws[(size_t)(b * 64 + i) * 1024 + h * 64 + d] = f2bf(oacc[dt][r]);
        }
}

// ---------------- host ----------------
extern "C" void kernel_launch(void* const* d_in, const int* in_sizes, int n_in,
                              void* d_out, int out_size, void* d_ws, size_t ws_size,
                              hipStream_t stream) {
    const float* x      = (const float*)d_in[0];
    const float* theta  = (const float*)d_in[1];
    const float* qkv_w  = (const float*)d_in[2];
    const float* qkv_b  = (const float*)d_in[3];
    const float* proj_w = (const float*)d_in[4];
    const float* proj_b = (const float*)d_in[5];
    const float* a_p    = (const float*)d_in[6];
    const float* b_p    = (const float*)d_in[7];
    const float* a_r    = (const float*)d_in[8];
    const float* b_r    = (const float*)d_in[9];
    float* out = (float*)d_out;

    char* ws = (char*)d_ws;
    unsigned short* xb    = (unsigned short*)(ws);                      // 32768*1024*2 = 67108864
    unsigned short* wqkv  = (unsigned short*)(ws + 67108864);           // 3072*1024*2  = 6291456
    unsigned short* wproj = (unsigned short*)(ws + 73400320);           // 1024*1024*2  = 2097152
    unsigned short* qkvb  = (unsigned short*)(ws + 75497472);           // 32768*3072*2 = 201326592
    unsigned short* ob    = (unsigned short*)(ws + 276824064);          // 32768*1024*2 = 67108864
    // total 343932928 bytes

    // converts
    cvt_kernel<<<2048, 256, 0, stream>>>(x,      xb,    33554432 / 4);
    cvt_kernel<<<1024, 256, 0, stream>>>(qkv_w,  wqkv,  3145728 / 4);
    cvt_kernel<<<512,  256, 0, stream>>>(proj_w, wproj, 1048576 / 4);

    // qkv GEMM: M=32768, N=3072
    gemm_bt<3072, 0><<<dim3(256 * 24), dim3(256), 0, stream>>>(xb, wqkv, qkv_b, nullptr, qkvb);

    // attention: one block per (window, head)
    attn_kernel<<<dim3(512 * 16), dim3(256), 0, stream>>>(qkvb, theta, a_p, b_p, a_r, b_r, ob);

    // proj GEMM: M=32768, N=1024 -> fp32 out
    gemm_bt<1024, 1><<<dim3(256 * 8), dim3(256), 0, stream>>>(ob, wproj, proj_b, out, nullptr);
}